// Round 10
// baseline (212.955 us; speedup 1.0000x reference)
//
#include <hip/hip_runtime.h>
#include <hip/hip_bf16.h>
#include <stdint.h>
#include <stddef.h>

typedef __bf16 bf16_t;
typedef __attribute__((ext_vector_type(8))) __bf16 bf16x8;   // 4 VGPRs, MFMA A/B operand
typedef __attribute__((ext_vector_type(4))) __bf16 bf16x4;   // 8B packed P store
typedef __attribute__((ext_vector_type(4))) float f32x4;     // MFMA C/D

#define MFMA_BF16(a, b, c) __builtin_amdgcn_mfma_f32_16x16x32_bf16((a), (b), (c), 0, 0, 0)

#define GLOAD_LDS(gsrc, ldst)                                                   \
  __builtin_amdgcn_global_load_lds(                                             \
      (const __attribute__((address_space(1))) unsigned int*)(gsrc),            \
      (__attribute__((address_space(3))) unsigned int*)(ldst), 16, 0, 0)

// ---------------- fused prep: dtype-detect + cvt_x + both weight transposes -----
// Every block re-derives the dtype flag from the SAME fixed 8KB sample of x
// (identical data -> identical decision). Block 0 publishes it. Flattened
// blockIdx dispatch:
//   [0, 2048)        cvt_x block               (2,2048,1024) f32 -> bf16
//   [2048, 5120)     W_attn transpose 32x32    (1024,3072) -> Wat (3072,1024)
//   [5120, 6144)     W_proj transpose 32x32    (1024,1024) -> Wpt (1024,1024)
__global__ __launch_bounds__(256) void prep(const void* __restrict__ x,
                                            const void* __restrict__ Wa,
                                            const void* __restrict__ Wp,
                                            bf16_t* __restrict__ xb,
                                            bf16_t* __restrict__ Wat,
                                            bf16_t* __restrict__ Wpt,
                                            int* __restrict__ flag) {
  __shared__ int dcnt;
  __shared__ bf16_t tile[32][33];

  const int tid = threadIdx.x;
  if (tid == 0) dcnt = 0;
  __syncthreads();
  {
    const unsigned short* p = (const unsigned short*)x + tid * 16;
    int local = 0;
#pragma unroll
    for (int i = 0; i < 16; ++i) {
      const int e = (p[i] >> 7) & 0xFF;
      if (e >= 0x8D) local++;
    }
    if (local) atomicAdd(&dcnt, local);
  }
  __syncthreads();
  const int isF32 = (dcnt > 4) ? 1 : 0;

  const int b = blockIdx.x;
  if (b == 0 && tid == 0) *flag = isF32;

  if (b < 2048) {
    if (!isF32) return;  // already bf16; GEMM reads x directly
    const size_t i = ((size_t)b * 256 + tid) * 8;
    const float4 a0 = *(const float4*)((const float*)x + i);
    const float4 a1 = *(const float4*)((const float*)x + i + 4);
    bf16x8 r;
    r[0] = (__bf16)a0.x; r[1] = (__bf16)a0.y; r[2] = (__bf16)a0.z; r[3] = (__bf16)a0.w;
    r[4] = (__bf16)a1.x; r[5] = (__bf16)a1.y; r[6] = (__bf16)a1.z; r[7] = (__bf16)a1.w;
    *(bf16x8*)(xb + i) = r;
    return;
  }

  const void* in;
  bf16_t* out;
  int R, C, bx, by;
  if (b < 5120) {
    const int idx = b - 2048;
    in = Wa; out = Wat; R = 1024; C = 3072;
    bx = idx % 96; by = idx / 96;
  } else {
    const int idx = b - 5120;
    in = Wp; out = Wpt; R = 1024; C = 1024;
    bx = idx & 31; by = idx >> 5;
  }
  const int tx = tid & 31, ty = tid >> 5;
  const int r0 = by * 32, c0 = bx * 32;
#pragma unroll
  for (int i = 0; i < 4; ++i) {
    const size_t idx2 = (size_t)(r0 + ty + i * 8) * C + (c0 + tx);
    tile[ty + i * 8][tx] = isF32 ? (bf16_t)((const float*)in)[idx2]
                                 : ((const bf16_t*)in)[idx2];
  }
  __syncthreads();
#pragma unroll
  for (int i = 0; i < 4; ++i)
    out[(size_t)(c0 + ty + i * 8) * R + (r0 + tx)] = tile[tx][ty + i * 8];
}

// ---------------- GEMM: C = A * Bt^T + bias --------------------------------------
// v10: staging via global_load_lds width=16 (m97/m151 pattern: HBM->LDS direct,
// no VGPR round-trip, no ds_write instructions, -32 staging VGPRs). LDS is
// LINEAR [128][64] per operand (gload_lds dest = wave-uniform base + lane*16).
// The resulting 16-way read conflicts on 128B-stride rows are tolerable in this
// 2-barrier regime (m97: 874 TF with the same layout; T2-null-at-2ph).
// Pool keeps 36.9KB so the MODE1 epilogue re-tile buffer (34.8KB) still fits.
// MODE 1: Q/K blocks re-tile via LDS -> 16B stores to Qs (pre-scaled) / Kb;
//         V-blocks (n0>=2048) transpose tile via LDS -> 16B stores to Vt.
// MODE 2: A = head-major attn out in Qs (h = k0>>6 exact at BK=64); plain C store.
#define GP 72
template <int MODE>
__global__ __launch_bounds__(256) void gemm_bt(const void* A0,
                        const bf16_t* __restrict__ xb,
                        const bf16_t* __restrict__ Bt,
                        const void* __restrict__ bias,
                        void* C,
                        bf16_t* __restrict__ Qs,
                        bf16_t* __restrict__ Kb,
                        bf16_t* __restrict__ dout_bf,
                        int M, int N, int K,
                        const int* __restrict__ flagp) {
  const int isF32 = *flagp;
  const bf16_t* A = (MODE == 1 && isF32) ? xb : (const bf16_t*)A0;
  bf16_t* Vt = dout_bf + (isF32 ? (size_t)4194304 : 0);  // d_out hi half if f32 out

  // pool sized 36864B (epilogue re-tile needs 34816B); As/Bs use the first 32KB.
  __shared__ __align__(16) unsigned char pool[128 * GP * 2 * 2];
  bf16_t* As = (bf16_t*)pool;             // [128][64] linear
  bf16_t* Bs = (bf16_t*)pool + 128 * 64;  // [128][64] linear

  const int tid = threadIdx.x;
  const int w = tid >> 6, lane = tid & 63;
  const int quad = lane >> 4, l16 = lane & 15;
  const int wm = w >> 1, wn = w & 1;
  const int m0 = blockIdx.y * 128, n0 = blockIdx.x * 128;

  // staging slot for issue it: g = it*256 + tid -> row = g>>3, col = (g&7)*8;
  // LDS elem offset = g*8 = it*2048 + w*512 + lane*8 (base wave-uniform).
  auto gsrcA = [&](int k0, int it) -> const bf16_t* {
    const int g = it * 256 + tid;
    const int row = g >> 3, col = (g & 7) * 8;
    const int m = m0 + row;
    if (MODE == 2) {
      const size_t aoff =
          ((size_t)((m >> 11) * 16 + (k0 >> 6)) * 2048 + (m & 2047)) * 64 + col;
      return A + aoff;
    }
    return A + (size_t)m * K + (k0 + col);
  };
  auto gsrcB = [&](int k0, int it) -> const bf16_t* {
    const int g = it * 256 + tid;
    const int row = g >> 3, col = (g & 7) * 8;
    return Bt + (size_t)(n0 + row) * K + (k0 + col);
  };

  f32x4 acc[4][4];
#pragma unroll
  for (int i = 0; i < 4; ++i)
#pragma unroll
    for (int j = 0; j < 4; ++j) acc[i][j] = f32x4{0.f, 0.f, 0.f, 0.f};

  for (int k0 = 0; k0 < K; k0 += 64) {
    __syncthreads();  // prev iter's fragment reads done before LDS overwrite
#pragma unroll
    for (int it = 0; it < 4; ++it) {
      GLOAD_LDS(gsrcA(k0, it), As + it * 2048 + w * 512);
      GLOAD_LDS(gsrcB(k0, it), Bs + it * 2048 + w * 512);
    }
    __syncthreads();  // drains vmcnt(0) -> staged data visible

#pragma unroll
    for (int kc = 0; kc < 2; ++kc) {
      bf16x8 af[4], bfr[4];
#pragma unroll
      for (int i = 0; i < 4; ++i)
        af[i] = *(const bf16x8*)&As[(wm * 64 + i * 16 + l16) * 64 + kc * 32 + quad * 8];
#pragma unroll
      for (int j = 0; j < 4; ++j)
        bfr[j] = *(const bf16x8*)&Bs[(wn * 64 + j * 16 + l16) * 64 + kc * 32 + quad * 8];
#pragma unroll
      for (int i = 0; i < 4; ++i)
#pragma unroll
        for (int j = 0; j < 4; ++j) acc[i][j] = MFMA_BF16(af[i], bfr[j], acc[i][j]);
    }
  }

  // ---------------- epilogue — C/D layout: row = quad*4 + r, col = l16 ----------
  if (MODE == 1 && n0 >= 2048) {
    // V blocks: transpose tile via LDS, then coalesced 16B stores to Vt (B,H,D,S).
    bf16_t* tp = (bf16_t*)pool;  // [n_local][m_local], stride 136
    __syncthreads();
#pragma unroll
    for (int j = 0; j < 4; ++j) {
      const int n_l = wn * 64 + j * 16 + l16;
      const int n = n0 + n_l;
      const float bj = isF32 ? ((const float*)bias)[n] : (float)((const bf16_t*)bias)[n];
#pragma unroll
      for (int i = 0; i < 4; ++i) {
#pragma unroll
        for (int r = 0; r < 4; ++r) {
          const int m_l = wm * 64 + i * 16 + quad * 4 + r;
          tp[n_l * 136 + m_l] = (bf16_t)(acc[i][j][r] + bj);
        }
      }
    }
    __syncthreads();
    const int b = m0 >> 11, s0 = m0 & 2047;
#pragma unroll
    for (int seg = 0; seg < 8; ++seg) {
      const int idx = seg * 256 + tid;
      const int n_l = idx >> 4, ms = (idx & 15) * 8;
      const bf16x8 v8 = *(const bf16x8*)&tp[n_l * 136 + ms];
      const int e = (n0 + n_l) & 1023, h = e >> 6, d = e & 63;
      *(bf16x8*)(Vt + ((size_t)(b * 16 + h) * 64 + d) * 2048 + s0 + ms) = v8;
    }
    return;
  }

  if (MODE == 1) {
    // Q/K blocks: re-tile [m_l][n_l] via LDS -> coalesced 16B stores.
    bf16_t* tp = (bf16_t*)pool;  // [m_local][n_local], stride 136
    __syncthreads();
    const bool isQ = (n0 < 1024);
    const float sc = isQ ? 0.18033688011f : 1.0f;  // Q pre-scale: 1/8 * log2(e)
#pragma unroll
    for (int j = 0; j < 4; ++j) {
      const int n_l = wn * 64 + j * 16 + l16;
      const int n = n0 + n_l;
      const float bj = isF32 ? ((const float*)bias)[n] : (float)((const bf16_t*)bias)[n];
#pragma unroll
      for (int i = 0; i < 4; ++i) {
#pragma unroll
        for (int r = 0; r < 4; ++r) {
          const int m_l = wm * 64 + i * 16 + quad * 4 + r;
          tp[m_l * 136 + n_l] = (bf16_t)((acc[i][j][r] + bj) * sc);
        }
      }
    }
    __syncthreads();
    bf16_t* dst = isQ ? Qs : Kb;
#pragma unroll
    for (int seg = 0; seg < 8; ++seg) {
      const int idx = seg * 256 + tid;
      const int m_l = idx >> 4, ns = (idx & 15) * 8;
      const bf16x8 v8 = *(const bf16x8*)&tp[m_l * 136 + ns];
      const int m = m0 + m_l;
      const int e = (n0 + ns) & 1023, h = e >> 6, d = e & 63;
      const int bb = m >> 11, s = m & 2047;
      *(bf16x8*)(dst + (((size_t)(bb * 16 + h) * 2048 + s) * 64 + d)) = v8;
    }
    return;
  }

#pragma unroll
  for (int j = 0; j < 4; ++j) {
    const int n = n0 + wn * 64 + j * 16 + l16;
    const float bj = isF32 ? ((const float*)bias)[n] : (float)((const bf16_t*)bias)[n];
#pragma unroll
    for (int i = 0; i < 4; ++i) {
      const int mbase = m0 + wm * 64 + i * 16 + quad * 4;
#pragma unroll
      for (int r = 0; r < 4; ++r) {
        const int m = mbase + r;
        const float v = acc[i][j][r] + bj;
        if (isF32) ((float*)C)[(size_t)m * N + n] = v;
        else       ((bf16_t*)C)[(size_t)m * N + n] = (bf16_t)v;
      }
    }
  }
}

// ---------------- causal flash attention (exact R4/v4 kernel — proven 45.0us) ----
// FROZEN: v5 (setprio), v6 (32x32), v7 (V-direct), v8 (32q/wave) all regressed.
// 4-wave (256-thread) blocks over a 64-row q-tile, 16 q-rows per wave.
// 1024 blocks, LDS 27.6KB; balanced decode: any stride-256 residue class sums
// to exactly 66 tile-iters. Swapped QK^T -> packed 8B P stores; NO-MAX exp2.
#define AP 72
#define PSP 72
__global__ __launch_bounds__(256, 5) void attn_kernel(bf16_t* QO,
                                                      const bf16_t* __restrict__ Kb,
                                                      const bf16_t* __restrict__ dout_bf,
                                                      const int* __restrict__ flagp) {
  const int isF32 = *flagp;
  const bf16_t* Vt = dout_bf + (isF32 ? (size_t)4194304 : 0);

  __shared__ __align__(16) bf16_t Ks[64 * AP];      // [key][d]
  __shared__ __align__(16) bf16_t Vs[64 * AP];      // [d][key]
  __shared__ __align__(16) bf16_t Ps[4][16 * PSP];  // per-wave P [q_local][key]

  const int bid = blockIdx.x;
  const int g = bid >> 5, bh = bid & 31;
  const int qt = (g < 16) ? (31 - g) : (g - 16);    // balanced + longest-first

  const int tid = threadIdx.x, w = tid >> 6, lane = tid & 63;
  const int quad = lane >> 4, l16 = lane & 15;

  bf16_t* Q = QO + (size_t)bh * 2048 * 64;
  const bf16_t* K = Kb + (size_t)bh * 2048 * 64;
  const bf16_t* V = Vt + (size_t)bh * 64 * 2048;

  const int qrow = qt * 64 + w * 16;                // this wave's 16 q-rows
  const int nkt = qt + 1;                           // causal 64-key tiles (block)

  // Q fragments (B-operand of swapped QK: cols = q)
  bf16x8 qf[2];
#pragma unroll
  for (int kk = 0; kk < 2; ++kk)
    qf[kk] = *(const bf16x8*)(Q + (size_t)(qrow + l16) * 64 + kk * 32 + quad * 8);

  f32x4 oacc[4];
  float lsum = 0.f;
#pragma unroll
  for (int jd = 0; jd < 4; ++jd) oacc[jd] = f32x4{0.f, 0.f, 0.f, 0.f};

  // staging: 256 threads x 2 x 16B per buffer = full 64x64 bf16 tile
  const int srow8 = lane >> 3;         // 0..7
  const int scol8 = (lane & 7) * 8;    // 0..56

  auto loadK = [&](int kt, int it) -> bf16x8 {
    const int row = (w + it * 4) * 8 + srow8;
    return *(const bf16x8*)(K + (size_t)(kt * 64 + row) * 64 + scol8);
  };
  auto loadV = [&](int kt, int it) -> bf16x8 {
    const int row = (w + it * 4) * 8 + srow8;
    return *(const bf16x8*)(V + (size_t)row * 2048 + kt * 64 + scol8);
  };

  bf16x8 kv[2], vv[2];
#pragma unroll
  for (int it = 0; it < 2; ++it) { kv[it] = loadK(0, it); vv[it] = loadV(0, it); }

  for (int kt = 0; kt < nkt; ++kt) {
    __syncthreads();  // prev iter's Ks/Vs fragment reads done
#pragma unroll
    for (int it = 0; it < 2; ++it) {
      const int row = (w + it * 4) * 8 + srow8;
      *(bf16x8*)&Ks[row * AP + scol8] = kv[it];  // Ks[key][d]
      *(bf16x8*)&Vs[row * AP + scol8] = vv[it];  // Vs[d][key]
    }
    __syncthreads();

    // prefetch next tile; stays in flight through QK/softmax/PV
    if (kt + 1 < nkt) {
#pragma unroll
      for (int it = 0; it < 2; ++it) { kv[it] = loadK(kt + 1, it); vv[it] = loadV(kt + 1, it); }
    }

    const int kbase = kt * 64;
    // swapped S = K Q^T: row = key (j*16 + quad*4 + r), col = q (l16)
    f32x4 s[4];
#pragma unroll
    for (int j = 0; j < 4; ++j) {
      const bf16x8 kf0 = *(const bf16x8*)&Ks[(j * 16 + l16) * AP + quad * 8];
      const bf16x8 kf1 = *(const bf16x8*)&Ks[(j * 16 + l16) * AP + 32 + quad * 8];
      f32x4 z = f32x4{0.f, 0.f, 0.f, 0.f};
      z = MFMA_BF16(kf0, qf[0], z);
      s[j] = MFMA_BF16(kf1, qf[1], z);
    }

    if (kbase + 63 > qrow) {  // diagonal: tile max key > wave min q
      const int qg = qrow + l16;
#pragma unroll
      for (int j = 0; j < 4; ++j) {
        const int key = kbase + j * 16 + quad * 4;
#pragma unroll
        for (int r = 0; r < 4; ++r)
          if (key + r > qg) s[j][r] = -1e30f;
      }
    }

    // no-max softmax: p = exp2(s); lane-local partial of l (one q per lane);
    // 4 consecutive keys per reg quad -> one packed 8B store per j
#pragma unroll
    for (int j = 0; j < 4; ++j) {
      bf16x4 pk;
#pragma unroll
      for (int r = 0; r < 4; ++r) {
        const float p = exp2f(s[j][r]);
        lsum += p;
        pk[r] = (__bf16)p;
      }
      *(bf16x4*)&Ps[w][l16 * PSP + j * 16 + quad * 4] = pk;
    }

    // PV (same-wave RAW on Ps, no barrier): A = P rows=q, B = Vs cols=d
#pragma unroll
    for (int kk = 0; kk < 2; ++kk) {
      const bf16x8 pf = *(const bf16x8*)&Ps[w][l16 * PSP + kk * 32 + quad * 8];
#pragma unroll
      for (int jd = 0; jd < 4; ++jd) {
        const bf16x8 vf = *(const bf16x8*)&Vs[(jd * 16 + l16) * AP + kk * 32 + quad * 8];
        oacc[jd] = MFMA_BF16(pf, vf, oacc[jd]);
      }
    }
  }

  // l reduction: partials for q=l16 live in lanes {l16, l16+16, l16+32, l16+48}
  lsum += __shfl_xor(lsum, 16);
  lsum += __shfl_xor(lsum, 32);

  // O /= l, write in place over this wave's own Q rows (private -> race-free)
#pragma unroll
  for (int r = 0; r < 4; ++r) {
    const float lr = fmaxf(__shfl(lsum, quad * 4 + r, 16), 1e-30f);
    const int q = qrow + quad * 4 + r;
#pragma unroll
    for (int jd = 0; jd < 4; ++jd) {
      const int d = jd * 16 + l16;
      Q[(size_t)q * 64 + d] = (bf16_t)(oacc[jd][r] / lr);
    }
  }
}

// ---------------- launch ----------------------------------------------------------
extern "C" void kernel_launch(void* const* d_in, const int* in_sizes, int n_in,
                              void* d_out, int out_size, void* d_ws, size_t ws_size,
                              hipStream_t stream) {
  const void* x      = d_in[0];   // (2,2048,1024)
  const void* W_attn = d_in[1];   // (1024,3072)
  const void* b_attn = d_in[2];   // (3072,)
  const void* W_proj = d_in[3];   // (1024,1024)
  const void* b_proj = d_in[4];   // (1024,)

  // ws: flag + Qs 8MB + Kb 8MB + Wat 6MB + Wpt 2MB = 24MB.
  // d_out (16MB when f32 out): lo half = xb (bf16 x), hi half = Vt; both dead
  // before proj GEMM overwrites d_out. (bf16 out: xb unused, Vt = lo half.)
  char* ws = (char*)d_ws;
  size_t off = 0;
  auto alloc = [&](size_t bytes) {
    char* p = ws + off;
    off += (bytes + 255) & ~(size_t)255;
    return p;
  };
  int*    flag = (int*)alloc(256);
  bf16_t* Qs   = (bf16_t*)alloc((size_t)32 * 2048 * 64 * 2);   // Q, then O in place
  bf16_t* Kb   = (bf16_t*)alloc((size_t)32 * 2048 * 64 * 2);
  bf16_t* Wat  = (bf16_t*)alloc((size_t)3072 * 1024 * 2);      // W_attn^T (N,K) bf16
  bf16_t* Wpt  = (bf16_t*)alloc((size_t)1024 * 1024 * 2);      // W_proj^T bf16
  bf16_t* dout_bf = (bf16_t*)d_out;

  // 1 launch: detect + cvt_x + both transposes
  prep<<<dim3(6144), 256, 0, stream>>>(x, W_attn, W_proj, dout_bf, Wat, Wpt, flag);

  gemm_bt<1><<<dim3(3072 / 128, 4096 / 128), 256, 0, stream>>>(
      x, dout_bf, Wat, b_attn, nullptr, Qs, Kb, dout_bf, 4096, 3072, 1024, flag);

  attn_kernel<<<dim3(1024), 256, 0, stream>>>(Qs, Kb, dout_bf, flag);

  gemm_bt<2><<<dim3(1024 / 128, 4096 / 128), 256, 0, stream>>>(
      Qs, nullptr, Wpt, b_proj, d_out, nullptr, nullptr, dout_bf, 4096, 1024, 1024, flag);
}

// Round 11
// 186.796 us; speedup vs baseline: 1.1400x; 1.1400x over previous
//
#include <hip/hip_runtime.h>
#include <hip/hip_bf16.h>
#include <stdint.h>
#include <stddef.h>

typedef __bf16 bf16_t;
typedef __attribute__((ext_vector_type(8))) __bf16 bf16x8;   // 4 VGPRs, MFMA A/B operand
typedef __attribute__((ext_vector_type(4))) __bf16 bf16x4;   // 8B packed P store
typedef __attribute__((ext_vector_type(4))) float f32x4;     // MFMA C/D

#define MFMA_BF16(a, b, c) __builtin_amdgcn_mfma_f32_16x16x32_bf16((a), (b), (c), 0, 0, 0)

// ---------------- fused prep: dtype-detect + cvt_x + both weight transposes -----
// Every block re-derives the dtype flag from the SAME fixed 8KB sample of x
// (identical data -> identical decision). Block 0 publishes it. Flattened
// blockIdx dispatch:
//   [0, 2048)        cvt_x block               (2,2048,1024) f32 -> bf16
//   [2048, 5120)     W_attn transpose 32x32    (1024,3072) -> Wat (3072,1024)
//   [5120, 6144)     W_proj transpose 32x32    (1024,1024) -> Wpt (1024,1024)
__global__ __launch_bounds__(256) void prep(const void* __restrict__ x,
                                            const void* __restrict__ Wa,
                                            const void* __restrict__ Wp,
                                            bf16_t* __restrict__ xb,
                                            bf16_t* __restrict__ Wat,
                                            bf16_t* __restrict__ Wpt,
                                            int* __restrict__ flag) {
  __shared__ int dcnt;
  __shared__ bf16_t tile[32][33];

  const int tid = threadIdx.x;
  if (tid == 0) dcnt = 0;
  __syncthreads();
  {
    const unsigned short* p = (const unsigned short*)x + tid * 16;
    int local = 0;
#pragma unroll
    for (int i = 0; i < 16; ++i) {
      const int e = (p[i] >> 7) & 0xFF;
      if (e >= 0x8D) local++;
    }
    if (local) atomicAdd(&dcnt, local);
  }
  __syncthreads();
  const int isF32 = (dcnt > 4) ? 1 : 0;

  const int b = blockIdx.x;
  if (b == 0 && tid == 0) *flag = isF32;

  if (b < 2048) {
    if (!isF32) return;  // already bf16; GEMM reads x directly
    const size_t i = ((size_t)b * 256 + tid) * 8;
    const float4 a0 = *(const float4*)((const float*)x + i);
    const float4 a1 = *(const float4*)((const float*)x + i + 4);
    bf16x8 r;
    r[0] = (__bf16)a0.x; r[1] = (__bf16)a0.y; r[2] = (__bf16)a0.z; r[3] = (__bf16)a0.w;
    r[4] = (__bf16)a1.x; r[5] = (__bf16)a1.y; r[6] = (__bf16)a1.z; r[7] = (__bf16)a1.w;
    *(bf16x8*)(xb + i) = r;
    return;
  }

  const void* in;
  bf16_t* out;
  int R, C, bx, by;
  if (b < 5120) {
    const int idx = b - 2048;
    in = Wa; out = Wat; R = 1024; C = 3072;
    bx = idx % 96; by = idx / 96;
  } else {
    const int idx = b - 5120;
    in = Wp; out = Wpt; R = 1024; C = 1024;
    bx = idx & 31; by = idx >> 5;
  }
  const int tx = tid & 31, ty = tid >> 5;
  const int r0 = by * 32, c0 = bx * 32;
#pragma unroll
  for (int i = 0; i < 4; ++i) {
    const size_t idx2 = (size_t)(r0 + ty + i * 8) * C + (c0 + tx);
    tile[ty + i * 8][tx] = isF32 ? (bf16_t)((const float*)in)[idx2]
                                 : ((const bf16_t*)in)[idx2];
  }
  __syncthreads();
#pragma unroll
  for (int i = 0; i < 4; ++i)
    out[(size_t)(c0 + ty + i * 8) * R + (r0 + tx)] = tile[tx][ty + i * 8];
}

// ---------------- GEMM: C = A * Bt^T + bias --------------------------------------
// Main loop = R4/R8 reg-staging version (known-good; the v10 global_load_lds port
// regressed: linear LDS -> 16-way read conflicts AND no prefetch overlap).
// 128xBNT tile, BK=64, register-prefetch staging, padded LDS stride 72.
// BNT=128 (MODE 1): 2x2 waves, 64x64 each. BNT=64 (MODE 2): 4x1 waves, 32x64
// each -> 512 blocks = 2 blocks/CU (was 1/CU: zero cross-block overlap).
// MODE 1: Q/K blocks re-tile via LDS -> 16B stores to Qs (pre-scaled) / Kb;
//         V-blocks (n0>=2048) transpose tile via LDS -> 16B stores to Vt.
// MODE 2: A = head-major attn out in Qs (h = k0>>6 exact at BK=64); plain C store.
#define GP 72
template <int MODE, int BNT>
__global__ __launch_bounds__(256) void gemm_bt(const void* A0,
                        const bf16_t* __restrict__ xb,
                        const bf16_t* __restrict__ Bt,
                        const void* __restrict__ bias,
                        void* C,
                        bf16_t* __restrict__ Qs,
                        bf16_t* __restrict__ Kb,
                        bf16_t* __restrict__ dout_bf,
                        int M, int N, int K,
                        const int* __restrict__ flagp) {
  const int isF32 = *flagp;
  const bf16_t* A = (MODE == 1 && isF32) ? xb : (const bf16_t*)A0;
  bf16_t* Vt = dout_bf + (isF32 ? (size_t)4194304 : 0);  // d_out hi half if f32 out

  constexpr int MI = (BNT == 128) ? 4 : 2;   // M sub-tiles per wave
  constexpr int NB = BNT / 32;               // B staging issues (4 or 2)

  __shared__ __align__(16) unsigned char pool[128 * GP * 2 * 2];
  bf16_t* As = (bf16_t*)pool;
  bf16_t* Bs = (bf16_t*)pool + 128 * GP;

  const int tid = threadIdx.x;
  const int w = tid >> 6, lane = tid & 63;
  const int quad = lane >> 4, l16 = lane & 15;
  const int wm = (BNT == 128) ? (w >> 1) : w;
  const int wn = (BNT == 128) ? (w & 1) : 0;
  const int m0 = blockIdx.y * 128, n0 = blockIdx.x * BNT;

  auto loadA = [&](int k0, int it) -> bf16x8 {
    const int g = it * 256 + tid;
    const int row = g >> 3, col = (g & 7) * 8;
    const int m = m0 + row;
    if (MODE == 2) {
      const size_t aoff =
          ((size_t)((m >> 11) * 16 + (k0 >> 6)) * 2048 + (m & 2047)) * 64 + col;
      return *(const bf16x8*)(A + aoff);
    }
    return *(const bf16x8*)(A + (size_t)m * K + (k0 + col));
  };
  auto loadB = [&](int k0, int it) -> bf16x8 {
    const int g = it * 256 + tid;
    const int row = g >> 3, col = (g & 7) * 8;
    return *(const bf16x8*)(Bt + (size_t)(n0 + row) * K + (k0 + col));
  };

  f32x4 acc[MI][4];
#pragma unroll
  for (int i = 0; i < MI; ++i)
#pragma unroll
    for (int j = 0; j < 4; ++j) acc[i][j] = f32x4{0.f, 0.f, 0.f, 0.f};

  bf16x8 va[4], vb[NB];
#pragma unroll
  for (int it = 0; it < 4; ++it) va[it] = loadA(0, it);
#pragma unroll
  for (int it = 0; it < NB; ++it) vb[it] = loadB(0, it);

  for (int k0 = 0; k0 < K; k0 += 64) {
    __syncthreads();  // prev iter's fragment reads done before LDS overwrite
#pragma unroll
    for (int it = 0; it < 4; ++it) {
      const int g = it * 256 + tid;
      const int row = g >> 3, col = (g & 7) * 8;
      *(bf16x8*)&As[row * GP + col] = va[it];
    }
#pragma unroll
    for (int it = 0; it < NB; ++it) {
      const int g = it * 256 + tid;
      const int row = g >> 3, col = (g & 7) * 8;
      *(bf16x8*)&Bs[row * GP + col] = vb[it];
    }
    __syncthreads();

    // prefetch next K-slice; completes during the MFMAs below
    if (k0 + 64 < K) {
#pragma unroll
      for (int it = 0; it < 4; ++it) va[it] = loadA(k0 + 64, it);
#pragma unroll
      for (int it = 0; it < NB; ++it) vb[it] = loadB(k0 + 64, it);
    }

#pragma unroll
    for (int kc = 0; kc < 2; ++kc) {
      bf16x8 af[MI], bfr[4];
#pragma unroll
      for (int i = 0; i < MI; ++i)
        af[i] = *(const bf16x8*)&As[(wm * (MI * 16) + i * 16 + l16) * GP + kc * 32 + quad * 8];
#pragma unroll
      for (int j = 0; j < 4; ++j)
        bfr[j] = *(const bf16x8*)&Bs[(wn * 64 + j * 16 + l16) * GP + kc * 32 + quad * 8];
#pragma unroll
      for (int i = 0; i < MI; ++i)
#pragma unroll
        for (int j = 0; j < 4; ++j) acc[i][j] = MFMA_BF16(af[i], bfr[j], acc[i][j]);
    }
  }

  // ---------------- epilogue — C/D layout: row = quad*4 + r, col = l16 ----------
  if (MODE == 1 && n0 >= 2048) {
    // V blocks: transpose tile via LDS, then coalesced 16B stores to Vt (B,H,D,S).
    bf16_t* tp = (bf16_t*)pool;  // [n_local][m_local], stride 136
    __syncthreads();
#pragma unroll
    for (int j = 0; j < 4; ++j) {
      const int n_l = wn * 64 + j * 16 + l16;
      const int n = n0 + n_l;
      const float bj = isF32 ? ((const float*)bias)[n] : (float)((const bf16_t*)bias)[n];
#pragma unroll
      for (int i = 0; i < MI; ++i) {
#pragma unroll
        for (int r = 0; r < 4; ++r) {
          const int m_l = wm * (MI * 16) + i * 16 + quad * 4 + r;
          tp[n_l * 136 + m_l] = (bf16_t)(acc[i][j][r] + bj);
        }
      }
    }
    __syncthreads();
    const int b = m0 >> 11, s0 = m0 & 2047;
#pragma unroll
    for (int seg = 0; seg < 8; ++seg) {
      const int idx = seg * 256 + tid;
      const int n_l = idx >> 4, ms = (idx & 15) * 8;
      const bf16x8 v8 = *(const bf16x8*)&tp[n_l * 136 + ms];
      const int e = (n0 + n_l) & 1023, h = e >> 6, d = e & 63;
      *(bf16x8*)(Vt + ((size_t)(b * 16 + h) * 64 + d) * 2048 + s0 + ms) = v8;
    }
    return;
  }

  if (MODE == 1) {
    // Q/K blocks: re-tile [m_l][n_l] via LDS -> coalesced 16B stores.
    bf16_t* tp = (bf16_t*)pool;  // [m_local][n_local], stride 136
    __syncthreads();
    const bool isQ = (n0 < 1024);
    const float sc = isQ ? 0.18033688011f : 1.0f;  // Q pre-scale: 1/8 * log2(e)
#pragma unroll
    for (int j = 0; j < 4; ++j) {
      const int n_l = wn * 64 + j * 16 + l16;
      const int n = n0 + n_l;
      const float bj = isF32 ? ((const float*)bias)[n] : (float)((const bf16_t*)bias)[n];
#pragma unroll
      for (int i = 0; i < MI; ++i) {
#pragma unroll
        for (int r = 0; r < 4; ++r) {
          const int m_l = wm * (MI * 16) + i * 16 + quad * 4 + r;
          tp[m_l * 136 + n_l] = (bf16_t)((acc[i][j][r] + bj) * sc);
        }
      }
    }
    __syncthreads();
    bf16_t* dst = isQ ? Qs : Kb;
#pragma unroll
    for (int seg = 0; seg < 8; ++seg) {
      const int idx = seg * 256 + tid;
      const int m_l = idx >> 4, ns = (idx & 15) * 8;
      const bf16x8 v8 = *(const bf16x8*)&tp[m_l * 136 + ns];
      const int m = m0 + m_l;
      const int e = (n0 + ns) & 1023, h = e >> 6, d = e & 63;
      const int bb = m >> 11, s = m & 2047;
      *(bf16x8*)(dst + (((size_t)(bb * 16 + h) * 2048 + s) * 64 + d)) = v8;
    }
    return;
  }

#pragma unroll
  for (int j = 0; j < 4; ++j) {
    const int n = n0 + wn * 64 + j * 16 + l16;
    const float bj = isF32 ? ((const float*)bias)[n] : (float)((const bf16_t*)bias)[n];
#pragma unroll
    for (int i = 0; i < MI; ++i) {
      const int mbase = m0 + wm * (MI * 16) + i * 16 + quad * 4;
#pragma unroll
      for (int r = 0; r < 4; ++r) {
        const int m = mbase + r;
        const float v = acc[i][j][r] + bj;
        if (isF32) ((float*)C)[(size_t)m * N + n] = v;
        else       ((bf16_t*)C)[(size_t)m * N + n] = (bf16_t)v;
      }
    }
  }
}

// ---------------- causal flash attention (exact R4/v4 kernel — proven 45.0us) ----
// FROZEN: v5 (setprio), v6 (32x32), v7 (V-direct), v8 (32q/wave) all regressed.
// 4-wave (256-thread) blocks over a 64-row q-tile, 16 q-rows per wave.
// 1024 blocks, LDS 27.6KB; balanced decode: any stride-256 residue class sums
// to exactly 66 tile-iters. Swapped QK^T -> packed 8B P stores; NO-MAX exp2.
#define AP 72
#define PSP 72
__global__ __launch_bounds__(256, 5) void attn_kernel(bf16_t* QO,
                                                      const bf16_t* __restrict__ Kb,
                                                      const bf16_t* __restrict__ dout_bf,
                                                      const int* __restrict__ flagp) {
  const int isF32 = *flagp;
  const bf16_t* Vt = dout_bf + (isF32 ? (size_t)4194304 : 0);

  __shared__ __align__(16) bf16_t Ks[64 * AP];      // [key][d]
  __shared__ __align__(16) bf16_t Vs[64 * AP];      // [d][key]
  __shared__ __align__(16) bf16_t Ps[4][16 * PSP];  // per-wave P [q_local][key]

  const int bid = blockIdx.x;
  const int g = bid >> 5, bh = bid & 31;
  const int qt = (g < 16) ? (31 - g) : (g - 16);    // balanced + longest-first

  const int tid = threadIdx.x, w = tid >> 6, lane = tid & 63;
  const int quad = lane >> 4, l16 = lane & 15;

  bf16_t* Q = QO + (size_t)bh * 2048 * 64;
  const bf16_t* K = Kb + (size_t)bh * 2048 * 64;
  const bf16_t* V = Vt + (size_t)bh * 64 * 2048;

  const int qrow = qt * 64 + w * 16;                // this wave's 16 q-rows
  const int nkt = qt + 1;                           // causal 64-key tiles (block)

  // Q fragments (B-operand of swapped QK: cols = q)
  bf16x8 qf[2];
#pragma unroll
  for (int kk = 0; kk < 2; ++kk)
    qf[kk] = *(const bf16x8*)(Q + (size_t)(qrow + l16) * 64 + kk * 32 + quad * 8);

  f32x4 oacc[4];
  float lsum = 0.f;
#pragma unroll
  for (int jd = 0; jd < 4; ++jd) oacc[jd] = f32x4{0.f, 0.f, 0.f, 0.f};

  // staging: 256 threads x 2 x 16B per buffer = full 64x64 bf16 tile
  const int srow8 = lane >> 3;         // 0..7
  const int scol8 = (lane & 7) * 8;    // 0..56

  auto loadK = [&](int kt, int it) -> bf16x8 {
    const int row = (w + it * 4) * 8 + srow8;
    return *(const bf16x8*)(K + (size_t)(kt * 64 + row) * 64 + scol8);
  };
  auto loadV = [&](int kt, int it) -> bf16x8 {
    const int row = (w + it * 4) * 8 + srow8;
    return *(const bf16x8*)(V + (size_t)row * 2048 + kt * 64 + scol8);
  };

  bf16x8 kv[2], vv[2];
#pragma unroll
  for (int it = 0; it < 2; ++it) { kv[it] = loadK(0, it); vv[it] = loadV(0, it); }

  for (int kt = 0; kt < nkt; ++kt) {
    __syncthreads();  // prev iter's Ks/Vs fragment reads done
#pragma unroll
    for (int it = 0; it < 2; ++it) {
      const int row = (w + it * 4) * 8 + srow8;
      *(bf16x8*)&Ks[row * AP + scol8] = kv[it];  // Ks[key][d]
      *(bf16x8*)&Vs[row * AP + scol8] = vv[it];  // Vs[d][key]
    }
    __syncthreads();

    // prefetch next tile; stays in flight through QK/softmax/PV
    if (kt + 1 < nkt) {
#pragma unroll
      for (int it = 0; it < 2; ++it) { kv[it] = loadK(kt + 1, it); vv[it] = loadV(kt + 1, it); }
    }

    const int kbase = kt * 64;
    // swapped S = K Q^T: row = key (j*16 + quad*4 + r), col = q (l16)
    f32x4 s[4];
#pragma unroll
    for (int j = 0; j < 4; ++j) {
      const bf16x8 kf0 = *(const bf16x8*)&Ks[(j * 16 + l16) * AP + quad * 8];
      const bf16x8 kf1 = *(const bf16x8*)&Ks[(j * 16 + l16) * AP + 32 + quad * 8];
      f32x4 z = f32x4{0.f, 0.f, 0.f, 0.f};
      z = MFMA_BF16(kf0, qf[0], z);
      s[j] = MFMA_BF16(kf1, qf[1], z);
    }

    if (kbase + 63 > qrow) {  // diagonal: tile max key > wave min q
      const int qg = qrow + l16;
#pragma unroll
      for (int j = 0; j < 4; ++j) {
        const int key = kbase + j * 16 + quad * 4;
#pragma unroll
        for (int r = 0; r < 4; ++r)
          if (key + r > qg) s[j][r] = -1e30f;
      }
    }

    // no-max softmax: p = exp2(s); lane-local partial of l (one q per lane);
    // 4 consecutive keys per reg quad -> one packed 8B store per j
#pragma unroll
    for (int j = 0; j < 4; ++j) {
      bf16x4 pk;
#pragma unroll
      for (int r = 0; r < 4; ++r) {
        const float p = exp2f(s[j][r]);
        lsum += p;
        pk[r] = (__bf16)p;
      }
      *(bf16x4*)&Ps[w][l16 * PSP + j * 16 + quad * 4] = pk;
    }

    // PV (same-wave RAW on Ps, no barrier): A = P rows=q, B = Vs cols=d
#pragma unroll
    for (int kk = 0; kk < 2; ++kk) {
      const bf16x8 pf = *(const bf16x8*)&Ps[w][l16 * PSP + kk * 32 + quad * 8];
#pragma unroll
      for (int jd = 0; jd < 4; ++jd) {
        const bf16x8 vf = *(const bf16x8*)&Vs[(jd * 16 + l16) * AP + kk * 32 + quad * 8];
        oacc[jd] = MFMA_BF16(pf, vf, oacc[jd]);
      }
    }
  }

  // l reduction: partials for q=l16 live in lanes {l16, l16+16, l16+32, l16+48}
  lsum += __shfl_xor(lsum, 16);
  lsum += __shfl_xor(lsum, 32);

  // O /= l, write in place over this wave's own Q rows (private -> race-free)
#pragma unroll
  for (int r = 0; r < 4; ++r) {
    const float lr = fmaxf(__shfl(lsum, quad * 4 + r, 16), 1e-30f);
    const int q = qrow + quad * 4 + r;
#pragma unroll
    for (int jd = 0; jd < 4; ++jd) {
      const int d = jd * 16 + l16;
      Q[(size_t)q * 64 + d] = (bf16_t)(oacc[jd][r] / lr);
    }
  }
}

// ---------------- launch ----------------------------------------------------------
extern "C" void kernel_launch(void* const* d_in, const int* in_sizes, int n_in,
                              void* d_out, int out_size, void* d_ws, size_t ws_size,
                              hipStream_t stream) {
  const void* x      = d_in[0];   // (2,2048,1024)
  const void* W_attn = d_in[1];   // (1024,3072)
  const void* b_attn = d_in[2];   // (3072,)
  const void* W_proj = d_in[3];   // (1024,1024)
  const void* b_proj = d_in[4];   // (1024,)

  // ws: flag + Qs 8MB + Kb 8MB + Wat 6MB + Wpt 2MB = 24MB.
  // d_out (16MB when f32 out): lo half = xb (bf16 x), hi half = Vt; both dead
  // before proj GEMM overwrites d_out. (bf16 out: xb unused, Vt = lo half.)
  char* ws = (char*)d_ws;
  size_t off = 0;
  auto alloc = [&](size_t bytes) {
    char* p = ws + off;
    off += (bytes + 255) & ~(size_t)255;
    return p;
  };
  int*    flag = (int*)alloc(256);
  bf16_t* Qs   = (bf16_t*)alloc((size_t)32 * 2048 * 64 * 2);   // Q, then O in place
  bf16_t* Kb   = (bf16_t*)alloc((size_t)32 * 2048 * 64 * 2);
  bf16_t* Wat  = (bf16_t*)alloc((size_t)3072 * 1024 * 2);      // W_attn^T (N,K) bf16
  bf16_t* Wpt  = (bf16_t*)alloc((size_t)1024 * 1024 * 2);      // W_proj^T bf16
  bf16_t* dout_bf = (bf16_t*)d_out;

  // 1 launch: detect + cvt_x + both transposes
  prep<<<dim3(6144), 256, 0, stream>>>(x, W_attn, W_proj, dout_bf, Wat, Wpt, flag);

  gemm_bt<1, 128><<<dim3(3072 / 128, 4096 / 128), 256, 0, stream>>>(
      x, dout_bf, Wat, b_attn, nullptr, Qs, Kb, dout_bf, 4096, 3072, 1024, flag);

  attn_kernel<<<dim3(1024), 256, 0, stream>>>(Qs, Kb, dout_bf, flag);

  gemm_bt<2, 64><<<dim3(1024 / 64, 4096 / 128), 256, 0, stream>>>(
      Qs, nullptr, Wpt, b_proj, d_out, nullptr, nullptr, dout_bf, 4096, 1024, 1024, flag);
}

// Round 12
// 184.965 us; speedup vs baseline: 1.1513x; 1.0099x over previous
//
#include <hip/hip_runtime.h>
#include <hip/hip_bf16.h>
#include <stdint.h>
#include <stddef.h>

typedef __bf16 bf16_t;
typedef __attribute__((ext_vector_type(8))) __bf16 bf16x8;   // 4 VGPRs, MFMA A/B operand
typedef __attribute__((ext_vector_type(4))) __bf16 bf16x4;   // 8B packed P store
typedef __attribute__((ext_vector_type(4))) float f32x4;     // MFMA C/D

#define MFMA_BF16(a, b, c) __builtin_amdgcn_mfma_f32_16x16x32_bf16((a), (b), (c), 0, 0, 0)

// ---------------- fused prep: dtype-detect + cvt_x + both weight transposes -----
// Every block re-derives the dtype flag from the SAME fixed 8KB sample of x
// (identical data -> identical decision). Block 0 publishes it. Flattened
// blockIdx dispatch:
//   [0, 2048)        cvt_x block               (2,2048,1024) f32 -> bf16
//   [2048, 2816)     W_attn transpose 64x64    (1024,3072) -> Wat (3072,1024)
//   [2816, 3072)     W_proj transpose 64x64    (1024,1024) -> Wpt (1024,1024)
// v2: 64x64 transpose tiles (1024 blocks, was 4096 of 32x32) + ushort2-packed
// writes: each 32-lane half-wave stores 64 consecutive rows = 128B coalesced
// segments (was 2B stores in 64B segments). LDS 64x65 (65 = 1 mod 32 -> clean).
__global__ __launch_bounds__(256) void prep(const void* __restrict__ x,
                                            const void* __restrict__ Wa,
                                            const void* __restrict__ Wp,
                                            bf16_t* __restrict__ xb,
                                            bf16_t* __restrict__ Wat,
                                            bf16_t* __restrict__ Wpt,
                                            int* __restrict__ flag) {
  __shared__ int dcnt;
  __shared__ bf16_t t64[64][65];

  const int tid = threadIdx.x;
  if (tid == 0) dcnt = 0;
  __syncthreads();
  {
    const unsigned short* p = (const unsigned short*)x + tid * 16;
    int local = 0;
#pragma unroll
    for (int i = 0; i < 16; ++i) {
      const int e = (p[i] >> 7) & 0xFF;
      if (e >= 0x8D) local++;
    }
    if (local) atomicAdd(&dcnt, local);
  }
  __syncthreads();
  const int isF32 = (dcnt > 4) ? 1 : 0;

  const int b = blockIdx.x;
  if (b == 0 && tid == 0) *flag = isF32;

  if (b < 2048) {
    if (!isF32) return;  // already bf16; GEMM reads x directly
    const size_t i = ((size_t)b * 256 + tid) * 8;
    const float4 a0 = *(const float4*)((const float*)x + i);
    const float4 a1 = *(const float4*)((const float*)x + i + 4);
    bf16x8 r;
    r[0] = (__bf16)a0.x; r[1] = (__bf16)a0.y; r[2] = (__bf16)a0.z; r[3] = (__bf16)a0.w;
    r[4] = (__bf16)a1.x; r[5] = (__bf16)a1.y; r[6] = (__bf16)a1.z; r[7] = (__bf16)a1.w;
    *(bf16x8*)(xb + i) = r;
    return;
  }

  // transpose: out[c][r] = in[r][c], 64x64 tile
  const void* in;
  bf16_t* out;
  int R, C, bx, by;
  if (b < 2816) {
    const int idx = b - 2048;
    in = Wa; out = Wat; R = 1024; C = 3072;
    bx = idx % 48; by = idx / 48;
  } else {
    const int idx = b - 2816;
    in = Wp; out = Wpt; R = 1024; C = 1024;
    bx = idx & 15; by = idx >> 4;
  }
  const int r0 = by * 64, c0 = bx * 64;

  // read: wave wv covers row (wv + i*4), 64 lanes = 64 consecutive cols (coalesced)
  const int wv = tid >> 6, lane = tid & 63;
#pragma unroll
  for (int i = 0; i < 16; ++i) {
    const int r = wv + i * 4;
    const size_t idx2 = (size_t)(r0 + r) * C + (c0 + lane);
    t64[r][lane] = isF32 ? (bf16_t)((const float*)in)[idx2]
                         : ((const bf16_t*)in)[idx2];
  }
  __syncthreads();

  // write: half-wave (32 lanes) covers one col's 64 rows as 32 x ushort2 = 128B
  const int half = lane >> 5, rp = lane & 31;
#pragma unroll
  for (int j = 0; j < 8; ++j) {
    const int c_l = wv * 16 + j * 2 + half;
    const unsigned lo = __builtin_bit_cast(unsigned short, t64[2 * rp][c_l]);
    const unsigned hi = __builtin_bit_cast(unsigned short, t64[2 * rp + 1][c_l]);
    *(unsigned*)((unsigned short*)out + (size_t)(c0 + c_l) * R + r0 + 2 * rp) =
        lo | (hi << 16);
  }
}

// ---------------- GEMM: C = A * Bt^T + bias --------------------------------------
// Main loop = R4/R8 reg-staging version (FROZEN: matches m151's 646 TF structural
// ceiling; gload_lds port (R10) and depth-2 (R5, VGPR occupancy step) regressed).
// 128xBNT tile, BK=64, register-prefetch staging, padded LDS stride 72.
// BNT=128 (MODE 1): 2x2 waves, 64x64 each. BNT=64 (MODE 2): 4x1 waves, 32x64
// each -> 512 blocks = 2 blocks/CU (R11: confirmed -3us).
// MODE 1: Q/K blocks re-tile via LDS -> 16B stores to Qs (pre-scaled) / Kb;
//         V-blocks (n0>=2048) transpose tile via LDS -> 16B stores to Vt.
// MODE 2: A = head-major attn out in Qs (h = k0>>6 exact at BK=64); plain C store.
#define GP 72
template <int MODE, int BNT>
__global__ __launch_bounds__(256) void gemm_bt(const void* A0,
                        const bf16_t* __restrict__ xb,
                        const bf16_t* __restrict__ Bt,
                        const void* __restrict__ bias,
                        void* C,
                        bf16_t* __restrict__ Qs,
                        bf16_t* __restrict__ Kb,
                        bf16_t* __restrict__ dout_bf,
                        int M, int N, int K,
                        const int* __restrict__ flagp) {
  const int isF32 = *flagp;
  const bf16_t* A = (MODE == 1 && isF32) ? xb : (const bf16_t*)A0;
  bf16_t* Vt = dout_bf + (isF32 ? (size_t)4194304 : 0);  // d_out hi half if f32 out

  constexpr int MI = (BNT == 128) ? 4 : 2;   // M sub-tiles per wave
  constexpr int NB = BNT / 32;               // B staging issues (4 or 2)

  __shared__ __align__(16) unsigned char pool[128 * GP * 2 * 2];
  bf16_t* As = (bf16_t*)pool;
  bf16_t* Bs = (bf16_t*)pool + 128 * GP;

  const int tid = threadIdx.x;
  const int w = tid >> 6, lane = tid & 63;
  const int quad = lane >> 4, l16 = lane & 15;
  const int wm = (BNT == 128) ? (w >> 1) : w;
  const int wn = (BNT == 128) ? (w & 1) : 0;
  const int m0 = blockIdx.y * 128, n0 = blockIdx.x * BNT;

  auto loadA = [&](int k0, int it) -> bf16x8 {
    const int g = it * 256 + tid;
    const int row = g >> 3, col = (g & 7) * 8;
    const int m = m0 + row;
    if (MODE == 2) {
      const size_t aoff =
          ((size_t)((m >> 11) * 16 + (k0 >> 6)) * 2048 + (m & 2047)) * 64 + col;
      return *(const bf16x8*)(A + aoff);
    }
    return *(const bf16x8*)(A + (size_t)m * K + (k0 + col));
  };
  auto loadB = [&](int k0, int it) -> bf16x8 {
    const int g = it * 256 + tid;
    const int row = g >> 3, col = (g & 7) * 8;
    return *(const bf16x8*)(Bt + (size_t)(n0 + row) * K + (k0 + col));
  };

  f32x4 acc[MI][4];
#pragma unroll
  for (int i = 0; i < MI; ++i)
#pragma unroll
    for (int j = 0; j < 4; ++j) acc[i][j] = f32x4{0.f, 0.f, 0.f, 0.f};

  bf16x8 va[4], vb[NB];
#pragma unroll
  for (int it = 0; it < 4; ++it) va[it] = loadA(0, it);
#pragma unroll
  for (int it = 0; it < NB; ++it) vb[it] = loadB(0, it);

  for (int k0 = 0; k0 < K; k0 += 64) {
    __syncthreads();  // prev iter's fragment reads done before LDS overwrite
#pragma unroll
    for (int it = 0; it < 4; ++it) {
      const int g = it * 256 + tid;
      const int row = g >> 3, col = (g & 7) * 8;
      *(bf16x8*)&As[row * GP + col] = va[it];
    }
#pragma unroll
    for (int it = 0; it < NB; ++it) {
      const int g = it * 256 + tid;
      const int row = g >> 3, col = (g & 7) * 8;
      *(bf16x8*)&Bs[row * GP + col] = vb[it];
    }
    __syncthreads();

    // prefetch next K-slice; completes during the MFMAs below
    if (k0 + 64 < K) {
#pragma unroll
      for (int it = 0; it < 4; ++it) va[it] = loadA(k0 + 64, it);
#pragma unroll
      for (int it = 0; it < NB; ++it) vb[it] = loadB(k0 + 64, it);
    }

#pragma unroll
    for (int kc = 0; kc < 2; ++kc) {
      bf16x8 af[MI], bfr[4];
#pragma unroll
      for (int i = 0; i < MI; ++i)
        af[i] = *(const bf16x8*)&As[(wm * (MI * 16) + i * 16 + l16) * GP + kc * 32 + quad * 8];
#pragma unroll
      for (int j = 0; j < 4; ++j)
        bfr[j] = *(const bf16x8*)&Bs[(wn * 64 + j * 16 + l16) * GP + kc * 32 + quad * 8];
#pragma unroll
      for (int i = 0; i < MI; ++i)
#pragma unroll
        for (int j = 0; j < 4; ++j) acc[i][j] = MFMA_BF16(af[i], bfr[j], acc[i][j]);
    }
  }

  // ---------------- epilogue — C/D layout: row = quad*4 + r, col = l16 ----------
  if (MODE == 1 && n0 >= 2048) {
    // V blocks: transpose tile via LDS, then coalesced 16B stores to Vt (B,H,D,S).
    bf16_t* tp = (bf16_t*)pool;  // [n_local][m_local], stride 136
    __syncthreads();
#pragma unroll
    for (int j = 0; j < 4; ++j) {
      const int n_l = wn * 64 + j * 16 + l16;
      const int n = n0 + n_l;
      const float bj = isF32 ? ((const float*)bias)[n] : (float)((const bf16_t*)bias)[n];
#pragma unroll
      for (int i = 0; i < MI; ++i) {
#pragma unroll
        for (int r = 0; r < 4; ++r) {
          const int m_l = wm * (MI * 16) + i * 16 + quad * 4 + r;
          tp[n_l * 136 + m_l] = (bf16_t)(acc[i][j][r] + bj);
        }
      }
    }
    __syncthreads();
    const int b = m0 >> 11, s0 = m0 & 2047;
#pragma unroll
    for (int seg = 0; seg < 8; ++seg) {
      const int idx = seg * 256 + tid;
      const int n_l = idx >> 4, ms = (idx & 15) * 8;
      const bf16x8 v8 = *(const bf16x8*)&tp[n_l * 136 + ms];
      const int e = (n0 + n_l) & 1023, h = e >> 6, d = e & 63;
      *(bf16x8*)(Vt + ((size_t)(b * 16 + h) * 64 + d) * 2048 + s0 + ms) = v8;
    }
    return;
  }

  if (MODE == 1) {
    // Q/K blocks: re-tile [m_l][n_l] via LDS -> coalesced 16B stores.
    bf16_t* tp = (bf16_t*)pool;  // [m_local][n_local], stride 136
    __syncthreads();
    const bool isQ = (n0 < 1024);
    const float sc = isQ ? 0.18033688011f : 1.0f;  // Q pre-scale: 1/8 * log2(e)
#pragma unroll
    for (int j = 0; j < 4; ++j) {
      const int n_l = wn * 64 + j * 16 + l16;
      const int n = n0 + n_l;
      const float bj = isF32 ? ((const float*)bias)[n] : (float)((const bf16_t*)bias)[n];
#pragma unroll
      for (int i = 0; i < MI; ++i) {
#pragma unroll
        for (int r = 0; r < 4; ++r) {
          const int m_l = wm * (MI * 16) + i * 16 + quad * 4 + r;
          tp[m_l * 136 + n_l] = (bf16_t)((acc[i][j][r] + bj) * sc);
        }
      }
    }
    __syncthreads();
    bf16_t* dst = isQ ? Qs : Kb;
#pragma unroll
    for (int seg = 0; seg < 8; ++seg) {
      const int idx = seg * 256 + tid;
      const int m_l = idx >> 4, ns = (idx & 15) * 8;
      const bf16x8 v8 = *(const bf16x8*)&tp[m_l * 136 + ns];
      const int m = m0 + m_l;
      const int e = (n0 + ns) & 1023, h = e >> 6, d = e & 63;
      const int bb = m >> 11, s = m & 2047;
      *(bf16x8*)(dst + (((size_t)(bb * 16 + h) * 2048 + s) * 64 + d)) = v8;
    }
    return;
  }

#pragma unroll
  for (int j = 0; j < 4; ++j) {
    const int n = n0 + wn * 64 + j * 16 + l16;
    const float bj = isF32 ? ((const float*)bias)[n] : (float)((const bf16_t*)bias)[n];
#pragma unroll
    for (int i = 0; i < MI; ++i) {
      const int mbase = m0 + wm * (MI * 16) + i * 16 + quad * 4;
#pragma unroll
      for (int r = 0; r < 4; ++r) {
        const int m = mbase + r;
        const float v = acc[i][j][r] + bj;
        if (isF32) ((float*)C)[(size_t)m * N + n] = v;
        else       ((bf16_t*)C)[(size_t)m * N + n] = (bf16_t)v;
      }
    }
  }
}

// ---------------- causal flash attention (exact R4/v4 kernel — proven 45.0us) ----
// FROZEN: v5 (setprio), v6 (32x32), v7 (V-direct), v8 (32q/wave) all regressed.
// At its LDS-instruction roofline (issue+conflict model reproduces 44us).
// 4-wave (256-thread) blocks over a 64-row q-tile, 16 q-rows per wave.
// 1024 blocks, LDS 27.6KB; balanced decode: any stride-256 residue class sums
// to exactly 66 tile-iters. Swapped QK^T -> packed 8B P stores; NO-MAX exp2.
#define AP 72
#define PSP 72
__global__ __launch_bounds__(256, 5) void attn_kernel(bf16_t* QO,
                                                      const bf16_t* __restrict__ Kb,
                                                      const bf16_t* __restrict__ dout_bf,
                                                      const int* __restrict__ flagp) {
  const int isF32 = *flagp;
  const bf16_t* Vt = dout_bf + (isF32 ? (size_t)4194304 : 0);

  __shared__ __align__(16) bf16_t Ks[64 * AP];      // [key][d]
  __shared__ __align__(16) bf16_t Vs[64 * AP];      // [d][key]
  __shared__ __align__(16) bf16_t Ps[4][16 * PSP];  // per-wave P [q_local][key]

  const int bid = blockIdx.x;
  const int g = bid >> 5, bh = bid & 31;
  const int qt = (g < 16) ? (31 - g) : (g - 16);    // balanced + longest-first

  const int tid = threadIdx.x, w = tid >> 6, lane = tid & 63;
  const int quad = lane >> 4, l16 = lane & 15;

  bf16_t* Q = QO + (size_t)bh * 2048 * 64;
  const bf16_t* K = Kb + (size_t)bh * 2048 * 64;
  const bf16_t* V = Vt + (size_t)bh * 64 * 2048;

  const int qrow = qt * 64 + w * 16;                // this wave's 16 q-rows
  const int nkt = qt + 1;                           // causal 64-key tiles (block)

  // Q fragments (B-operand of swapped QK: cols = q)
  bf16x8 qf[2];
#pragma unroll
  for (int kk = 0; kk < 2; ++kk)
    qf[kk] = *(const bf16x8*)(Q + (size_t)(qrow + l16) * 64 + kk * 32 + quad * 8);

  f32x4 oacc[4];
  float lsum = 0.f;
#pragma unroll
  for (int jd = 0; jd < 4; ++jd) oacc[jd] = f32x4{0.f, 0.f, 0.f, 0.f};

  // staging: 256 threads x 2 x 16B per buffer = full 64x64 bf16 tile
  const int srow8 = lane >> 3;         // 0..7
  const int scol8 = (lane & 7) * 8;    // 0..56

  auto loadK = [&](int kt, int it) -> bf16x8 {
    const int row = (w + it * 4) * 8 + srow8;
    return *(const bf16x8*)(K + (size_t)(kt * 64 + row) * 64 + scol8);
  };
  auto loadV = [&](int kt, int it) -> bf16x8 {
    const int row = (w + it * 4) * 8 + srow8;
    return *(const bf16x8*)(V + (size_t)row * 2048 + kt * 64 + scol8);
  };

  bf16x8 kv[2], vv[2];
#pragma unroll
  for (int it = 0; it < 2; ++it) { kv[it] = loadK(0, it); vv[it] = loadV(0, it); }

  for (int kt = 0; kt < nkt; ++kt) {
    __syncthreads();  // prev iter's Ks/Vs fragment reads done
#pragma unroll
    for (int it = 0; it < 2; ++it) {
      const int row = (w + it * 4) * 8 + srow8;
      *(bf16x8*)&Ks[row * AP + scol8] = kv[it];  // Ks[key][d]
      *(bf16x8*)&Vs[row * AP + scol8] = vv[it];  // Vs[d][key]
    }
    __syncthreads();

    // prefetch next tile; stays in flight through QK/softmax/PV
    if (kt + 1 < nkt) {
#pragma unroll
      for (int it = 0; it < 2; ++it) { kv[it] = loadK(kt + 1, it); vv[it] = loadV(kt + 1, it); }
    }

    const int kbase = kt * 64;
    // swapped S = K Q^T: row = key (j*16 + quad*4 + r), col = q (l16)
    f32x4 s[4];
#pragma unroll
    for (int j = 0; j < 4; ++j) {
      const bf16x8 kf0 = *(const bf16x8*)&Ks[(j * 16 + l16) * AP + quad * 8];
      const bf16x8 kf1 = *(const bf16x8*)&Ks[(j * 16 + l16) * AP + 32 + quad * 8];
      f32x4 z = f32x4{0.f, 0.f, 0.f, 0.f};
      z = MFMA_BF16(kf0, qf[0], z);
      s[j] = MFMA_BF16(kf1, qf[1], z);
    }

    if (kbase + 63 > qrow) {  // diagonal: tile max key > wave min q
      const int qg = qrow + l16;
#pragma unroll
      for (int j = 0; j < 4; ++j) {
        const int key = kbase + j * 16 + quad * 4;
#pragma unroll
        for (int r = 0; r < 4; ++r)
          if (key + r > qg) s[j][r] = -1e30f;
      }
    }

    // no-max softmax: p = exp2(s); lane-local partial of l (one q per lane);
    // 4 consecutive keys per reg quad -> one packed 8B store per j
#pragma unroll
    for (int j = 0; j < 4; ++j) {
      bf16x4 pk;
#pragma unroll
      for (int r = 0; r < 4; ++r) {
        const float p = exp2f(s[j][r]);
        lsum += p;
        pk[r] = (__bf16)p;
      }
      *(bf16x4*)&Ps[w][l16 * PSP + j * 16 + quad * 4] = pk;
    }

    // PV (same-wave RAW on Ps, no barrier): A = P rows=q, B = Vs cols=d
#pragma unroll
    for (int kk = 0; kk < 2; ++kk) {
      const bf16x8 pf = *(const bf16x8*)&Ps[w][l16 * PSP + kk * 32 + quad * 8];
#pragma unroll
      for (int jd = 0; jd < 4; ++jd) {
        const bf16x8 vf = *(const bf16x8*)&Vs[(jd * 16 + l16) * AP + kk * 32 + quad * 8];
        oacc[jd] = MFMA_BF16(pf, vf, oacc[jd]);
      }
    }
  }

  // l reduction: partials for q=l16 live in lanes {l16, l16+16, l16+32, l16+48}
  lsum += __shfl_xor(lsum, 16);
  lsum += __shfl_xor(lsum, 32);

  // O /= l, write in place over this wave's own Q rows (private -> race-free)
#pragma unroll
  for (int r = 0; r < 4; ++r) {
    const float lr = fmaxf(__shfl(lsum, quad * 4 + r, 16), 1e-30f);
    const int q = qrow + quad * 4 + r;
#pragma unroll
    for (int jd = 0; jd < 4; ++jd) {
      const int d = jd * 16 + l16;
      Q[(size_t)q * 64 + d] = (bf16_t)(oacc[jd][r] / lr);
    }
  }
}

// ---------------- launch ----------------------------------------------------------
extern "C" void kernel_launch(void* const* d_in, const int* in_sizes, int n_in,
                              void* d_out, int out_size, void* d_ws, size_t ws_size,
                              hipStream_t stream) {
  const void* x      = d_in[0];   // (2,2048,1024)
  const void* W_attn = d_in[1];   // (1024,3072)
  const void* b_attn = d_in[2];   // (3072,)
  const void* W_proj = d_in[3];   // (1024,1024)
  const void* b_proj = d_in[4];   // (1024,)

  // ws: flag + Qs 8MB + Kb 8MB + Wat 6MB + Wpt 2MB = 24MB.
  // d_out (16MB when f32 out): lo half = xb (bf16 x), hi half = Vt; both dead
  // before proj GEMM overwrites d_out. (bf16 out: xb unused, Vt = lo half.)
  char* ws = (char*)d_ws;
  size_t off = 0;
  auto alloc = [&](size_t bytes) {
    char* p = ws + off;
    off += (bytes + 255) & ~(size_t)255;
    return p;
  };
  int*    flag = (int*)alloc(256);
  bf16_t* Qs   = (bf16_t*)alloc((size_t)32 * 2048 * 64 * 2);   // Q, then O in place
  bf16_t* Kb   = (bf16_t*)alloc((size_t)32 * 2048 * 64 * 2);
  bf16_t* Wat  = (bf16_t*)alloc((size_t)3072 * 1024 * 2);      // W_attn^T (N,K) bf16
  bf16_t* Wpt  = (bf16_t*)alloc((size_t)1024 * 1024 * 2);      // W_proj^T bf16
  bf16_t* dout_bf = (bf16_t*)d_out;

  // 1 launch: detect + cvt_x + both transposes (64x64 tiles)
  prep<<<dim3(3072), 256, 0, stream>>>(x, W_attn, W_proj, dout_bf, Wat, Wpt, flag);

  gemm_bt<1, 128><<<dim3(3072 / 128, 4096 / 128), 256, 0, stream>>>(
      x, dout_bf, Wat, b_attn, nullptr, Qs, Kb, dout_bf, 4096, 3072, 1024, flag);

  attn_kernel<<<dim3(1024), 256, 0, stream>>>(Qs, Kb, dout_bf, flag);

  gemm_bt<2, 64><<<dim3(1024 / 64, 4096 / 128), 256, 0, stream>>>(
      Qs, nullptr, Wpt, b_proj, d_out, nullptr, nullptr, dout_bf, 4096, 1024, 1024, flag);
}